// Round 2
// baseline (1271.162 us; speedup 1.0000x reference)
//
#include <hip/hip_runtime.h>
#include <hip/hip_bf16.h>
#include <stdint.h>

typedef __attribute__((ext_vector_type(8))) short short8;
typedef __attribute__((ext_vector_type(4))) float floatx4;

__device__ __forceinline__ float bf2f(unsigned short u) {
    union { unsigned int ui; float f; } v; v.ui = ((unsigned int)u) << 16; return v.f;
}
__device__ __forceinline__ unsigned short f2bf(float f) {
    union { float f; unsigned int u; } v; v.f = f;
    unsigned int u = v.u;
    unsigned int r = (u + 0x7fffu + ((u >> 16) & 1u)) >> 16;
    return (unsigned short)r;
}

// ---------------- convert features fp32 -> bf16 ----------------
__global__ __launch_bounds__(256)
void convert_bf16(const float* __restrict__ in, unsigned short* __restrict__ out, int n4) {
    int i = blockIdx.x * blockDim.x + threadIdx.x;
    int stride = gridDim.x * blockDim.x;
    for (; i < n4; i += stride) {
        float4 v = ((const float4*)in)[i];
        ushort4 o;
        o.x = f2bf(v.x); o.y = f2bf(v.y); o.z = f2bf(v.z); o.w = f2bf(v.w);
        ((ushort4*)out)[i] = o;
    }
}

// ---------------- encode: enc[k][i] = valid ? idx : -1, padded to nvoxp ----------------
__global__ __launch_bounds__(256)
void encode_kernel(const int* __restrict__ nbr, const float* __restrict__ valid,
                   int* __restrict__ enc, int nvox, int nvoxp) {
    int k = blockIdx.y;
    int r = blockIdx.x * 256 + threadIdx.x;
    int v = -1;
    if (r < nvox) {
        float f = valid[(size_t)k * nvox + r];
        int ix = nbr[(size_t)k * nvox + r];
        v = (f != 0.f) ? ix : -1;
    }
    enc[(size_t)k * nvoxp + r] = v;
}

// ---------------- pack weights into B-fragment order ----------------
// Wp[kk][ks(2)][nt(4)][lane(64)][j(8)] = W[kk][cin = ks*32 + (lane>>4)*8 + j][cout = nt*16 + (lane&15)]
__global__ __launch_bounds__(256)
void pack_w(const float* __restrict__ W1, const float* __restrict__ W2,
            unsigned short* __restrict__ Wp1, unsigned short* __restrict__ Wp2) {
    int bi = blockIdx.x;               // 0..53
    const float* W = (bi < 27) ? W1 : W2;
    unsigned short* Wp = (bi < 27) ? Wp1 : Wp2;
    int kk = bi % 27;
    int t = threadIdx.x;
    int lane = t & 63, grp = t >> 6;
    int q = lane >> 4, l15 = lane & 15;
    for (int c8 = grp; c8 < 8; c8 += 4) {
        int ks = c8 >> 2, nt = c8 & 3;
        unsigned short* dst = Wp + (((kk*2 + ks)*4 + nt)*64 + lane)*8;
        const float* src = W + kk*4096 + (ks*32 + q*8)*64 + nt*16 + l15;
        #pragma unroll
        for (int j = 0; j < 8; ++j) dst[j] = f2bf(src[j*64]);
    }
}

// ---------------- gathered MFMA conv ----------------
// 32 voxels x 64 out-ch per wave (acc = 32 regs), depth-2 gather pipeline
// (3 av buffers), weights loaded FIRST each phase so the MFMA's vmcnt wait
// does not drain the in-flight prefetch gathers. enc read directly per-lane
// (no bpermute), prefetched 3-5 phases ahead.
__global__ __launch_bounds__(256, 4)
void conv_kernel(const unsigned short* __restrict__ xin, const int* __restrict__ enc,
                 const unsigned short* __restrict__ Wp, const unsigned short* __restrict__ zrow,
                 unsigned short* __restrict__ yout, float* __restrict__ sums,
                 int nvox, int nvoxp) {
    __shared__ float sred[128];
    int t = threadIdx.x;
    int wave = t >> 6, lane = t & 63;
    int q = lane >> 4, l15 = lane & 15;
    int m0 = blockIdx.x * 128 + wave * 32;   // 32 voxels per wave
    int qb = q * 8;                           // element offset within row half

    if (t < 128) sred[t] = 0.f;
    __syncthreads();

    floatx4 acc[2][4];
    #pragma unroll
    for (int s = 0; s < 2; ++s)
        #pragma unroll
        for (int nt = 0; nt < 4; ++nt) acc[s][nt] = (floatx4){0.f, 0.f, 0.f, 0.f};

    short8 av0[2][2], av1[2][2], av2[2][2];   // [ks][s], 16 VGPR each buffer
    short8 bv[2][4];                          // [ks][nt], 32 VGPR
    int es0[2], es1[2], es2[2];

#define ESLOAD(esX, kkv) { int kc_ = (kkv) > 26 ? 26 : (kkv); \
    const int* ep_ = enc + (size_t)kc_ * nvoxp + m0 + l15; \
    esX[0] = ep_[0]; esX[1] = ep_[16]; }

#define GATHER(avX, esX) { _Pragma("unroll") for (int s_ = 0; s_ < 2; ++s_) { \
    const unsigned short* rp_ = (esX[s_] >= 0) ? (xin + (size_t)esX[s_] * 64) : zrow; \
    avX[0][s_] = *(const short8*)(rp_ + qb); \
    avX[1][s_] = *(const short8*)(rp_ + 32 + qb); } }

#define BLOAD(kkv) { const unsigned short* wq_ = Wp + (kkv) * 4096 + lane * 8; \
    _Pragma("unroll") for (int ks_ = 0; ks_ < 2; ++ks_) \
    _Pragma("unroll") for (int nt_ = 0; nt_ < 4; ++nt_) \
        bv[ks_][nt_] = *(const short8*)(wq_ + ks_ * 2048 + nt_ * 512); }

#define MFMA_PHASE(avX) { __builtin_amdgcn_s_setprio(1); \
    _Pragma("unroll") for (int ks_ = 0; ks_ < 2; ++ks_) \
    _Pragma("unroll") for (int nt_ = 0; nt_ < 4; ++nt_) { \
        acc[0][nt_] = __builtin_amdgcn_mfma_f32_16x16x32_bf16(avX[ks_][0], bv[ks_][nt_], acc[0][nt_], 0, 0, 0); \
        acc[1][nt_] = __builtin_amdgcn_mfma_f32_16x16x32_bf16(avX[ks_][1], bv[ks_][nt_], acc[1][nt_], 0, 0, 0); } \
    __builtin_amdgcn_s_setprio(0); }

    // ---- prologue: prime es (3 ahead) and two gather buffers
    ESLOAD(es0, 0); ESLOAD(es1, 1); ESLOAD(es2, 2);
    GATHER(av0, es0);        // kk = 0
    ESLOAD(es0, 3);
    GATHER(av1, es1);        // kk = 1
    ESLOAD(es1, 4);

    // ---- main loop: 9 iterations x 3 phases = 27 taps
    // phase(kk): BLOAD(kk) -> GATHER(kk+2) -> ESLOAD(kk+5) -> SB -> MFMA(kk)
    #pragma unroll 1
    for (int it = 0; it < 9; ++it) {
        int kk = it * 3;

        BLOAD(kk);
        GATHER(av2, es2);            // kk+2
        ESLOAD(es2, kk + 5);
        __builtin_amdgcn_sched_barrier(0);
        MFMA_PHASE(av0);             // kk

        BLOAD(kk + 1);
        GATHER(av0, es0);            // kk+3
        ESLOAD(es0, kk + 6);
        __builtin_amdgcn_sched_barrier(0);
        MFMA_PHASE(av1);             // kk+1

        BLOAD(kk + 2);
        GATHER(av1, es1);            // kk+4
        ESLOAD(es1, kk + 7);
        __builtin_amdgcn_sched_barrier(0);
        MFMA_PHASE(av2);             // kk+2
    }

#undef ESLOAD
#undef GATHER
#undef BLOAD
#undef MFMA_PHASE

    // ---- store: D layout col = lane&15, row = q*4 + reg
    #pragma unroll
    for (int s = 0; s < 2; ++s) {
        int rowb = m0 + s*16 + q*4;
        #pragma unroll
        for (int r = 0; r < 4; ++r) {
            if (rowb + r < nvox) {
                unsigned short* yo = yout + (size_t)(rowb + r)*64 + l15;
                #pragma unroll
                for (int nt = 0; nt < 4; ++nt)
                    yo[nt*16] = f2bf(acc[s][nt][r]);
            }
        }
    }

    // ---- fused per-channel stats (pad rows have acc == 0)
    #pragma unroll
    for (int nt = 0; nt < 4; ++nt) {
        float s_ = 0.f, q_ = 0.f;
        #pragma unroll
        for (int s = 0; s < 2; ++s)
            #pragma unroll
            for (int r = 0; r < 4; ++r) {
                float v = acc[s][nt][r];
                s_ += v; q_ += v*v;
            }
        atomicAdd(&sred[nt*16 + l15], s_);
        atomicAdd(&sred[64 + nt*16 + l15], q_);
    }
    __syncthreads();
    if (t < 128) atomicAdd(&sums[t], sred[t]);
}

// ---------------- BN scale/bias ----------------
__global__ void finalize_kernel(const float* __restrict__ sums, const float* __restrict__ gamma,
                                const float* __restrict__ beta, float* __restrict__ ab, float invn) {
    int c = threadIdx.x;
    if (c < 64) {
        float mean = sums[c] * invn;
        float var  = sums[64 + c] * invn - mean*mean;
        float a = gamma[c] * rsqrtf(var + 1e-5f);
        ab[c] = a;
        ab[64 + c] = beta[c] - mean * a;
    }
}

// ---------------- BN1 + ReLU in place on y1 (bf16) ----------------
__global__ __launch_bounds__(256)
void bnrelu_kernel(unsigned short* __restrict__ y, const float* __restrict__ ab, int n4) {
    int i = blockIdx.x * blockDim.x + threadIdx.x;
    int stride = gridDim.x * blockDim.x;
    for (; i < n4; i += stride) {
        uint2 v = ((const uint2*)y)[i];
        int c0 = (i*4) & 63;
        float f0 = fmaxf(ab[c0]   * bf2f((unsigned short)(v.x & 0xffffu)) + ab[64 + c0],   0.f);
        float f1 = fmaxf(ab[c0+1] * bf2f((unsigned short)(v.x >> 16))     + ab[64 + c0+1], 0.f);
        float f2 = fmaxf(ab[c0+2] * bf2f((unsigned short)(v.y & 0xffffu)) + ab[64 + c0+2], 0.f);
        float f3 = fmaxf(ab[c0+3] * bf2f((unsigned short)(v.y >> 16))     + ab[64 + c0+3], 0.f);
        uint2 o;
        o.x = (unsigned int)f2bf(f0) | ((unsigned int)f2bf(f1) << 16);
        o.y = (unsigned int)f2bf(f2) | ((unsigned int)f2bf(f3) << 16);
        ((uint2*)y)[i] = o;
    }
}

// ---------------- epilogue: BN2 + identity + relu -> fp32 ----------------
__global__ __launch_bounds__(256)
void final_kernel(const unsigned short* __restrict__ y2, const float* __restrict__ feat,
                  const float* __restrict__ ab, float* __restrict__ out, int ntot2) {
    int i = blockIdx.x * blockDim.x + threadIdx.x;
    int stride = gridDim.x * blockDim.x;
    for (; i < ntot2; i += stride) {
        unsigned int v = ((const unsigned int*)y2)[i];
        int c0 = (i*2) & 63;
        float2 f = ((const float2*)feat)[i];
        float r0 = fmaxf(ab[c0]   * bf2f((unsigned short)(v & 0xffffu)) + ab[64 + c0]   + f.x, 0.f);
        float r1 = fmaxf(ab[c0+1] * bf2f((unsigned short)(v >> 16))     + ab[64 + c0+1] + f.y, 0.f);
        ((float2*)out)[i] = make_float2(r0, r1);
    }
}

extern "C" void kernel_launch(void* const* d_in, const int* in_sizes, int n_in,
                              void* d_out, int out_size, void* d_ws, size_t ws_size,
                              hipStream_t stream) {
    const float* features = (const float*)d_in[0];
    const int*   nbr      = (const int*)d_in[1];
    const float* valid    = (const float*)d_in[2];
    const float* W1       = (const float*)d_in[3];
    const float* gamma1   = (const float*)d_in[4];
    const float* beta1    = (const float*)d_in[5];
    const float* W2       = (const float*)d_in[6];
    const float* gamma2   = (const float*)d_in[7];
    const float* beta2    = (const float*)d_in[8];
    float* out = (float*)d_out;

    int nvox  = in_sizes[0] / 64;                 // 500000
    int nvoxp = (nvox + 255) & ~255;              // 500224 (multiple of 256 and 128)
    size_t featB = (size_t)nvox * 64 * 2;         // 64 MB bf16 feature map

    // d_out doubles as scratch until final_kernel overwrites all of it:
    //   [0, featB)        xb (bf16 features)
    //   [featB, 2*featB)  y1 (conv1 out, bf16; BN1+ReLU applied in place)
    char* ob = (char*)d_out;
    unsigned short* xb = (unsigned short*)ob;
    unsigned short* y1 = (unsigned short*)(ob + featB);

    // d_ws (~118.6 MB):
    //   [0, 2048)      stats: sums1, sums2, ab1, ab2 (128 floats each)
    //   [2048, 2176)   zero page (128 B)
    //   [4096, ..)     Wp1, Wp2 (216 KB each)
    //   [512K, +54MB)  enc (27 * nvoxp ints)
    //   then           y2 (bf16)
    char* ws = (char*)d_ws;
    float* stats = (float*)ws;
    float* sums1 = stats;
    float* sums2 = stats + 128;
    float* ab1   = stats + 256;
    float* ab2   = stats + 384;
    const unsigned short* zrow = (const unsigned short*)(ws + 2048);
    unsigned short* Wp1 = (unsigned short*)(ws + 4096);
    unsigned short* Wp2 = (unsigned short*)(ws + 4096 + 221184);
    int* enc = (int*)(ws + 524288);
    size_t encB = (size_t)27 * nvoxp * 4;          // 54,024,192
    unsigned short* y2 = (unsigned short*)(ws + 524288 + encB);

    hipMemsetAsync(ws, 0, 4096, stream);           // stats + zero page

    convert_bf16<<<2048, 256, 0, stream>>>(features, xb, nvox * 16);
    pack_w<<<54, 256, 0, stream>>>(W1, W2, Wp1, Wp2);
    dim3 eg(nvoxp / 256, 27);
    encode_kernel<<<eg, 256, 0, stream>>>(nbr, valid, enc, nvox, nvoxp);

    int convGrid = nvoxp / 128;   // 3908 blocks, 32 voxels/wave
    conv_kernel<<<convGrid, 256, 0, stream>>>(xb, enc, Wp1, zrow, y1, sums1, nvox, nvoxp);
    finalize_kernel<<<1, 64, 0, stream>>>(sums1, gamma1, beta1, ab1, 1.0f / nvox);
    bnrelu_kernel<<<2048, 256, 0, stream>>>(y1, ab1, nvox * 16);
    conv_kernel<<<convGrid, 256, 0, stream>>>(y1, enc, Wp2, zrow, y2, sums2, nvox, nvoxp);
    finalize_kernel<<<1, 64, 0, stream>>>(sums2, gamma2, beta2, ab2, 1.0f / nvox);
    final_kernel<<<4096, 256, 0, stream>>>(y2, features, ab2, out, nvox * 32);
}

// Round 3
// 837.193 us; speedup vs baseline: 1.5184x; 1.5184x over previous
//
#include <hip/hip_runtime.h>
#include <hip/hip_bf16.h>
#include <stdint.h>

typedef __attribute__((ext_vector_type(8))) short short8;
typedef __attribute__((ext_vector_type(4))) float floatx4;

__device__ __forceinline__ float bf2f(unsigned short u) {
    union { unsigned int ui; float f; } v; v.ui = ((unsigned int)u) << 16; return v.f;
}
__device__ __forceinline__ unsigned short f2bf(float f) {
    union { float f; unsigned int u; } v; v.f = f;
    unsigned int u = v.u;
    unsigned int r = (u + 0x7fffu + ((u >> 16) & 1u)) >> 16;
    return (unsigned short)r;
}

// ---------------- convert features fp32 -> bf16 ----------------
__global__ __launch_bounds__(256)
void convert_bf16(const float* __restrict__ in, unsigned short* __restrict__ out, int n4) {
    int i = blockIdx.x * blockDim.x + threadIdx.x;
    int stride = gridDim.x * blockDim.x;
    for (; i < n4; i += stride) {
        float4 v = ((const float4*)in)[i];
        ushort4 o;
        o.x = f2bf(v.x); o.y = f2bf(v.y); o.z = f2bf(v.z); o.w = f2bf(v.w);
        ((ushort4*)out)[i] = o;
    }
}

// ---------------- encode: enc[k][i] = valid ? idx : -1, padded to nvoxp ----------------
__global__ __launch_bounds__(256)
void encode_kernel(const int* __restrict__ nbr, const float* __restrict__ valid,
                   int* __restrict__ enc, int nvox, int nvoxp) {
    int k = blockIdx.y;
    int r = blockIdx.x * 256 + threadIdx.x;
    int v = -1;
    if (r < nvox) {
        float f = valid[(size_t)k * nvox + r];
        int ix = nbr[(size_t)k * nvox + r];
        v = (f != 0.f) ? ix : -1;
    }
    enc[(size_t)k * nvoxp + r] = v;
}

// ---------------- pack weights into B-fragment order ----------------
// Wp[kk][ks(2)][nt(4)][lane(64)][j(8)] = W[kk][cin = ks*32 + (lane>>4)*8 + j][cout = nt*16 + (lane&15)]
__global__ __launch_bounds__(256)
void pack_w(const float* __restrict__ W1, const float* __restrict__ W2,
            unsigned short* __restrict__ Wp1, unsigned short* __restrict__ Wp2) {
    int bi = blockIdx.x;               // 0..53
    const float* W = (bi < 27) ? W1 : W2;
    unsigned short* Wp = (bi < 27) ? Wp1 : Wp2;
    int kk = bi % 27;
    int t = threadIdx.x;
    int lane = t & 63, grp = t >> 6;
    int q = lane >> 4, l15 = lane & 15;
    for (int c8 = grp; c8 < 8; c8 += 4) {
        int ks = c8 >> 2, nt = c8 & 3;
        unsigned short* dst = Wp + (((kk*2 + ks)*4 + nt)*64 + lane)*8;
        const float* src = W + kk*4096 + (ks*32 + q*8)*64 + nt*16 + l15;
        #pragma unroll
        for (int j = 0; j < 8; ++j) dst[j] = f2bf(src[j*64]);
    }
}

// ---------------- gathered MFMA conv, depth-1 pipeline, 128-reg budget ----------------
// 32 voxels x 64 out-ch per wave: acc 32 AGPR, av ping-pong 2x16, bv 32 VGPR.
// Per phase: BLOAD(kk) -> [SB] -> GATHER(kk+1) + ESLOAD(kk+3) -> [SB] -> MFMA(kk).
// bv is issued BEFORE the prefetch gathers, so the MFMA's vmcnt wait on bv
// leaves the next-kk gathers in flight across the whole MFMA cluster.
__global__ __launch_bounds__(256, 4)
void conv_kernel(const unsigned short* __restrict__ xin, const int* __restrict__ enc,
                 const unsigned short* __restrict__ Wp, const unsigned short* __restrict__ zrow,
                 unsigned short* __restrict__ yout, float* __restrict__ sums,
                 int nvox, int nvoxp) {
    __shared__ float sred[128];
    int t = threadIdx.x;
    int wave = t >> 6, lane = t & 63;
    int q = lane >> 4, l15 = lane & 15;
    int m0 = blockIdx.x * 128 + wave * 32;   // 32 voxels per wave
    int qb = q * 8;                           // short offset within row half

    if (t < 128) sred[t] = 0.f;
    __syncthreads();

    floatx4 acc[2][4];
    #pragma unroll
    for (int s = 0; s < 2; ++s)
        #pragma unroll
        for (int nt = 0; nt < 4; ++nt) acc[s][nt] = (floatx4){0.f, 0.f, 0.f, 0.f};

    short8 avA[2][2], avB[2][2];   // [ks][s], 16 VGPR each
    short8 bv[2][4];               // [ks][nt], 32 VGPR
    int esA[2], esB[2];

    const int* encL = enc + m0 + l15;   // per-lane enc base

#define ESLOAD(esX, kkv) { int kc_ = (kkv) > 26 ? 26 : (kkv); \
    const int* ep_ = encL + kc_ * nvoxp; \
    esX[0] = ep_[0]; esX[1] = ep_[16]; }

#define GATHER(avX, esX) { _Pragma("unroll") for (int s_ = 0; s_ < 2; ++s_) { \
    const unsigned short* rp_ = (esX[s_] >= 0) ? (xin + ((size_t)(unsigned)esX[s_] << 6)) : zrow; \
    avX[0][s_] = *(const short8*)(rp_ + qb); \
    avX[1][s_] = *(const short8*)(rp_ + 32 + qb); } }

#define BLOAD(kkv) { const unsigned short* wq_ = Wp + (kkv) * 4096 + lane * 8; \
    _Pragma("unroll") for (int ks_ = 0; ks_ < 2; ++ks_) \
    _Pragma("unroll") for (int nt_ = 0; nt_ < 4; ++nt_) \
        bv[ks_][nt_] = *(const short8*)(wq_ + ks_ * 2048 + nt_ * 512); }

#define MFMA_PHASE(avX) { __builtin_amdgcn_s_setprio(1); \
    _Pragma("unroll") for (int ks_ = 0; ks_ < 2; ++ks_) \
    _Pragma("unroll") for (int nt_ = 0; nt_ < 4; ++nt_) { \
        acc[0][nt_] = __builtin_amdgcn_mfma_f32_16x16x32_bf16(avX[ks_][0], bv[ks_][nt_], acc[0][nt_], 0, 0, 0); \
        acc[1][nt_] = __builtin_amdgcn_mfma_f32_16x16x32_bf16(avX[ks_][1], bv[ks_][nt_], acc[1][nt_], 0, 0, 0); } \
    __builtin_amdgcn_s_setprio(0); }

    // ---- prologue: es for kk=0,1; gather kk=0 into avA; es for kk=2
    ESLOAD(esA, 0);
    ESLOAD(esB, 1);
    GATHER(avA, esA);
    ESLOAD(esA, 2);

    // ---- main loop: 13 double-phases (kk = 0..25) + epilogue kk = 26
    #pragma unroll 1
    for (int kkp = 0; kkp < 26; kkp += 2) {
        // phase even: weights(kk) first, then prefetch gathers(kk+1)
        BLOAD(kkp);
        __builtin_amdgcn_sched_barrier(0);
        GATHER(avB, esB);            // kk+1
        ESLOAD(esB, kkp + 3);
        __builtin_amdgcn_sched_barrier(0);
        MFMA_PHASE(avA);             // kk

        // phase odd
        BLOAD(kkp + 1);
        __builtin_amdgcn_sched_barrier(0);
        GATHER(avA, esA);            // kk+2
        ESLOAD(esA, kkp + 4);
        __builtin_amdgcn_sched_barrier(0);
        MFMA_PHASE(avB);             // kk+1
    }
    BLOAD(26);
    __builtin_amdgcn_sched_barrier(0);
    MFMA_PHASE(avA);                 // kk = 26

#undef ESLOAD
#undef GATHER
#undef BLOAD
#undef MFMA_PHASE

    // ---- store: D layout col = lane&15, row = q*4 + reg
    #pragma unroll
    for (int s = 0; s < 2; ++s) {
        int rowb = m0 + s*16 + q*4;
        #pragma unroll
        for (int r = 0; r < 4; ++r) {
            if (rowb + r < nvox) {
                unsigned short* yo = yout + (size_t)(rowb + r)*64 + l15;
                #pragma unroll
                for (int nt = 0; nt < 4; ++nt)
                    yo[nt*16] = f2bf(acc[s][nt][r]);
            }
        }
    }

    // ---- fused per-channel stats (pad rows have acc == 0)
    #pragma unroll
    for (int nt = 0; nt < 4; ++nt) {
        float s_ = 0.f, q_ = 0.f;
        #pragma unroll
        for (int s = 0; s < 2; ++s)
            #pragma unroll
            for (int r = 0; r < 4; ++r) {
                float v = acc[s][nt][r];
                s_ += v; q_ += v*v;
            }
        atomicAdd(&sred[nt*16 + l15], s_);
        atomicAdd(&sred[64 + nt*16 + l15], q_);
    }
    __syncthreads();
    if (t < 128) atomicAdd(&sums[t], sred[t]);
}

// ---------------- BN scale/bias ----------------
__global__ void finalize_kernel(const float* __restrict__ sums, const float* __restrict__ gamma,
                                const float* __restrict__ beta, float* __restrict__ ab, float invn) {
    int c = threadIdx.x;
    if (c < 64) {
        float mean = sums[c] * invn;
        float var  = sums[64 + c] * invn - mean*mean;
        float a = gamma[c] * rsqrtf(var + 1e-5f);
        ab[c] = a;
        ab[64 + c] = beta[c] - mean * a;
    }
}

// ---------------- BN1 + ReLU in place on y1 (bf16) ----------------
__global__ __launch_bounds__(256)
void bnrelu_kernel(unsigned short* __restrict__ y, const float* __restrict__ ab, int n4) {
    int i = blockIdx.x * blockDim.x + threadIdx.x;
    int stride = gridDim.x * blockDim.x;
    for (; i < n4; i += stride) {
        uint2 v = ((const uint2*)y)[i];
        int c0 = (i*4) & 63;
        float f0 = fmaxf(ab[c0]   * bf2f((unsigned short)(v.x & 0xffffu)) + ab[64 + c0],   0.f);
        float f1 = fmaxf(ab[c0+1] * bf2f((unsigned short)(v.x >> 16))     + ab[64 + c0+1], 0.f);
        float f2 = fmaxf(ab[c0+2] * bf2f((unsigned short)(v.y & 0xffffu)) + ab[64 + c0+2], 0.f);
        float f3 = fmaxf(ab[c0+3] * bf2f((unsigned short)(v.y >> 16))     + ab[64 + c0+3], 0.f);
        uint2 o;
        o.x = (unsigned int)f2bf(f0) | ((unsigned int)f2bf(f1) << 16);
        o.y = (unsigned int)f2bf(f2) | ((unsigned int)f2bf(f3) << 16);
        ((uint2*)y)[i] = o;
    }
}

// ---------------- epilogue: BN2 + identity + relu -> fp32 ----------------
__global__ __launch_bounds__(256)
void final_kernel(const unsigned short* __restrict__ y2, const float* __restrict__ feat,
                  const float* __restrict__ ab, float* __restrict__ out, int ntot2) {
    int i = blockIdx.x * blockDim.x + threadIdx.x;
    int stride = gridDim.x * blockDim.x;
    for (; i < ntot2; i += stride) {
        unsigned int v = ((const unsigned int*)y2)[i];
        int c0 = (i*2) & 63;
        float2 f = ((const float2*)feat)[i];
        float r0 = fmaxf(ab[c0]   * bf2f((unsigned short)(v & 0xffffu)) + ab[64 + c0]   + f.x, 0.f);
        float r1 = fmaxf(ab[c0+1] * bf2f((unsigned short)(v >> 16))     + ab[64 + c0+1] + f.y, 0.f);
        ((float2*)out)[i] = make_float2(r0, r1);
    }
}

extern "C" void kernel_launch(void* const* d_in, const int* in_sizes, int n_in,
                              void* d_out, int out_size, void* d_ws, size_t ws_size,
                              hipStream_t stream) {
    const float* features = (const float*)d_in[0];
    const int*   nbr      = (const int*)d_in[1];
    const float* valid    = (const float*)d_in[2];
    const float* W1       = (const float*)d_in[3];
    const float* gamma1   = (const float*)d_in[4];
    const float* beta1    = (const float*)d_in[5];
    const float* W2       = (const float*)d_in[6];
    const float* gamma2   = (const float*)d_in[7];
    const float* beta2    = (const float*)d_in[8];
    float* out = (float*)d_out;

    int nvox  = in_sizes[0] / 64;                 // 500000
    int nvoxp = (nvox + 255) & ~255;              // 500224 (multiple of 256 and 128)
    size_t featB = (size_t)nvox * 64 * 2;         // 64 MB bf16 feature map

    // d_out doubles as scratch until final_kernel overwrites all of it:
    //   [0, featB)        xb (bf16 features)
    //   [featB, 2*featB)  y1 (conv1 out, bf16; BN1+ReLU applied in place)
    char* ob = (char*)d_out;
    unsigned short* xb = (unsigned short*)ob;
    unsigned short* y1 = (unsigned short*)(ob + featB);

    // d_ws (~118.6 MB):
    //   [0, 2048)      stats: sums1, sums2, ab1, ab2 (128 floats each)
    //   [2048, 2176)   zero page (128 B)
    //   [4096, ..)     Wp1, Wp2 (216 KB each)
    //   [512K, +54MB)  enc (27 * nvoxp ints)
    //   then           y2 (bf16)
    char* ws = (char*)d_ws;
    float* stats = (float*)ws;
    float* sums1 = stats;
    float* sums2 = stats + 128;
    float* ab1   = stats + 256;
    float* ab2   = stats + 384;
    const unsigned short* zrow = (const unsigned short*)(ws + 2048);
    unsigned short* Wp1 = (unsigned short*)(ws + 4096);
    unsigned short* Wp2 = (unsigned short*)(ws + 4096 + 221184);
    int* enc = (int*)(ws + 524288);
    size_t encB = (size_t)27 * nvoxp * 4;          // 54,024,192
    unsigned short* y2 = (unsigned short*)(ws + 524288 + encB);

    hipMemsetAsync(ws, 0, 4096, stream);           // stats + zero page

    convert_bf16<<<2048, 256, 0, stream>>>(features, xb, nvox * 16);
    pack_w<<<54, 256, 0, stream>>>(W1, W2, Wp1, Wp2);
    dim3 eg(nvoxp / 256, 27);
    encode_kernel<<<eg, 256, 0, stream>>>(nbr, valid, enc, nvox, nvoxp);

    int convGrid = nvoxp / 128;   // 3908 blocks, 32 voxels/wave
    conv_kernel<<<convGrid, 256, 0, stream>>>(xb, enc, Wp1, zrow, y1, sums1, nvox, nvoxp);
    finalize_kernel<<<1, 64, 0, stream>>>(sums1, gamma1, beta1, ab1, 1.0f / nvox);
    bnrelu_kernel<<<2048, 256, 0, stream>>>(y1, ab1, nvox * 16);
    conv_kernel<<<convGrid, 256, 0, stream>>>(y1, enc, Wp2, zrow, y2, sums2, nvox, nvoxp);
    finalize_kernel<<<1, 64, 0, stream>>>(sums2, gamma2, beta2, ab2, 1.0f / nvox);
    final_kernel<<<4096, 256, 0, stream>>>(y2, features, ab2, out, nvox * 32);
}

// Round 4
// 800.550 us; speedup vs baseline: 1.5879x; 1.0458x over previous
//
#include <hip/hip_runtime.h>
#include <hip/hip_bf16.h>
#include <stdint.h>

typedef __attribute__((ext_vector_type(8))) short short8;
typedef __attribute__((ext_vector_type(4))) float floatx4;

__device__ __forceinline__ float bf2f(unsigned short u) {
    union { unsigned int ui; float f; } v; v.ui = ((unsigned int)u) << 16; return v.f;
}
__device__ __forceinline__ unsigned short f2bf(float f) {
    union { float f; unsigned int u; } v; v.f = f;
    unsigned int u = v.u;
    unsigned int r = (u + 0x7fffu + ((u >> 16) & 1u)) >> 16;
    return (unsigned short)r;
}

// ---------------- convert features fp32 -> bf16 ----------------
__global__ __launch_bounds__(256)
void convert_bf16(const float* __restrict__ in, unsigned short* __restrict__ out, int n4) {
    int i = blockIdx.x * blockDim.x + threadIdx.x;
    int stride = gridDim.x * blockDim.x;
    for (; i < n4; i += stride) {
        float4 v = ((const float4*)in)[i];
        ushort4 o;
        o.x = f2bf(v.x); o.y = f2bf(v.y); o.z = f2bf(v.z); o.w = f2bf(v.w);
        ((ushort4*)out)[i] = o;
    }
}

// ---------------- encode: enc[k][i] = valid ? idx : -1, padded to nvoxp ----------------
__global__ __launch_bounds__(256)
void encode_kernel(const int* __restrict__ nbr, const float* __restrict__ valid,
                   int* __restrict__ enc, int nvox, int nvoxp) {
    int k = blockIdx.y;
    int r = blockIdx.x * 256 + threadIdx.x;
    int v = -1;
    if (r < nvox) {
        float f = valid[(size_t)k * nvox + r];
        int ix = nbr[(size_t)k * nvox + r];
        v = (f != 0.f) ? ix : -1;
    }
    enc[(size_t)k * nvoxp + r] = v;
}

// ---------------- pack weights into B-fragment order ----------------
// Wp[kk][ks(2)][nt(4)][lane(64)][j(8)] = W[kk][cin = ks*32 + (lane>>4)*8 + j][cout = nt*16 + (lane&15)]
__global__ __launch_bounds__(256)
void pack_w(const float* __restrict__ W1, const float* __restrict__ W2,
            unsigned short* __restrict__ Wp1, unsigned short* __restrict__ Wp2) {
    int bi = blockIdx.x;               // 0..53
    const float* W = (bi < 27) ? W1 : W2;
    unsigned short* Wp = (bi < 27) ? Wp1 : Wp2;
    int kk = bi % 27;
    int t = threadIdx.x;
    int lane = t & 63, grp = t >> 6;
    int q = lane >> 4, l15 = lane & 15;
    for (int c8 = grp; c8 < 8; c8 += 4) {
        int ks = c8 >> 2, nt = c8 & 3;
        unsigned short* dst = Wp + (((kk*2 + ks)*4 + nt)*64 + lane)*8;
        const float* src = W + kk*4096 + (ks*32 + q*8)*64 + nt*16 + l15;
        #pragma unroll
        for (int j = 0; j < 8; ++j) dst[j] = f2bf(src[j*64]);
    }
}

// ---------------- gathered MFMA conv: LDS weight staging + counted-vmcnt pipeline ----
// 64 voxels x 64 out-ch per wave, 4 waves = 256 voxels per block.
// Per tap kk the block stages the 8 KB weight panel into LDS once (reg-staged:
// loads issued early, ds_write after the MFMA phase). B-operands come from LDS
// (lgkmcnt), so the vmcnt queue holds ONLY gathers/enc -> the av ping-pong
// prefetch survives the MFMA phase with counted waits. Raw s_barrier with
// lgkmcnt(0) only: gathers stay in flight across barriers.
__global__ __launch_bounds__(256, 3)
void conv_kernel(const unsigned short* __restrict__ xin, const int* __restrict__ enc,
                 const unsigned short* __restrict__ Wp, const unsigned short* __restrict__ zrow,
                 unsigned short* __restrict__ yout, float* __restrict__ sums,
                 int nvox, int nvoxp) {
    __shared__ unsigned short wbuf[2][4096];   // 2 x 8 KB weight panels
    __shared__ float sred[128];

    int t = threadIdx.x;
    int wave = t >> 6, lane = t & 63;
    int q = lane >> 4, l15 = lane & 15;
    int qb = q * 8;

    // bijective XCD swizzle: adjacent logical blocks (adjacent voxel ranges,
    // shared gather neighborhoods) land on the same XCD's L2.
    int nwg = gridDim.x;
    int q8 = nwg >> 3, r8 = nwg & 7;
    int xcd = blockIdx.x & 7, jj = blockIdx.x >> 3;
    int bswz = (xcd < r8 ? xcd * (q8 + 1) : r8 * (q8 + 1) + (xcd - r8) * q8) + jj;

    int m0 = bswz * 256 + wave * 64;   // 64 voxels per wave

    if (t < 128) sred[t] = 0.f;

    floatx4 acc[4][4];
    #pragma unroll
    for (int s = 0; s < 4; ++s)
        #pragma unroll
        for (int nt = 0; nt < 4; ++nt) acc[s][nt] = (floatx4){0.f, 0.f, 0.f, 0.f};

    short8 avA[2][4], avB[2][4];   // [ks][s], 32 VGPR each buffer
    uint4 wl0, wl1;                // weight staging registers (8 VGPR)
    int esA[4], esB[4];

    const int* encL = enc + m0 + l15;

#define ESLOAD(esX, kkv) { int kc_ = (kkv) > 26 ? 26 : (kkv); \
    const int* ep_ = encL + kc_ * nvoxp; \
    esX[0] = ep_[0]; esX[1] = ep_[16]; esX[2] = ep_[32]; esX[3] = ep_[48]; }

#define GATHER(avX, esX) { _Pragma("unroll") for (int s_ = 0; s_ < 4; ++s_) { \
    const unsigned short* rp_ = (esX[s_] >= 0) ? (xin + ((size_t)(unsigned)esX[s_] << 6)) : zrow; \
    avX[0][s_] = *(const short8*)(rp_ + qb); \
    avX[1][s_] = *(const short8*)(rp_ + 32 + qb); } }

#define STAGE_LOAD(kkv) { const uint4* wp_ = (const uint4*)(Wp + (kkv) * 4096) + t; \
    wl0 = wp_[0]; wl1 = wp_[256]; }

#define STAGE_WRITE(bufX) { ((uint4*)(bufX))[t] = wl0; ((uint4*)(bufX))[t + 256] = wl1; }

#define MFMA_PHASE(avX, wb_) { __builtin_amdgcn_s_setprio(1); \
    _Pragma("unroll") for (int ks_ = 0; ks_ < 2; ++ks_) \
    _Pragma("unroll") for (int nt_ = 0; nt_ < 4; ++nt_) { \
        short8 bv_ = *(const short8*)((wb_) + ((ks_ * 4 + nt_) * 64 + lane) * 8); \
        _Pragma("unroll") for (int s_ = 0; s_ < 4; ++s_) \
            acc[s_][nt_] = __builtin_amdgcn_mfma_f32_16x16x32_bf16(avX[ks_][s_], bv_, acc[s_][nt_], 0, 0, 0); } \
    __builtin_amdgcn_s_setprio(0); }

// lgkmcnt(0) ensures my ds_write/ds_read done; vmcnt deliberately NOT drained
// (in-flight gathers survive the barrier; compiler emits counted vmcnt at uses).
#define PIPE_BARRIER() { __builtin_amdgcn_sched_barrier(0); \
    asm volatile("s_waitcnt lgkmcnt(0)" ::: "memory"); \
    __builtin_amdgcn_s_barrier(); \
    __builtin_amdgcn_sched_barrier(0); }

    // ---- prologue: es(0),es(1); stage tap0 -> wbuf0; gather tap0; es(2)
    ESLOAD(esA, 0);
    ESLOAD(esB, 1);
    STAGE_LOAD(0);
    GATHER(avA, esA);
    ESLOAD(esA, 2);
    STAGE_WRITE(wbuf[0]);
    PIPE_BARRIER();

    // ---- main loop: 13 x (E,O) covers taps 0..25; epilogue tap 26
    // E(kk):  stage W(kk+1)->wbuf1 | gather tap kk+1 | es(kk+3) | MFMA tap kk  (wbuf0)
    // O(kk):  stage W(kk+2)->wbuf0 | gather tap kk+2 | es(kk+4) | MFMA tap kk+1(wbuf1)
    #pragma unroll 1
    for (int kk = 0; kk < 26; kk += 2) {
        STAGE_LOAD(kk + 1);
        GATHER(avB, esB);
        ESLOAD(esB, kk + 3);
        __builtin_amdgcn_sched_barrier(0);
        MFMA_PHASE(avA, wbuf[0]);
        __builtin_amdgcn_sched_barrier(0);
        STAGE_WRITE(wbuf[1]);
        PIPE_BARRIER();

        STAGE_LOAD(kk + 2);
        GATHER(avA, esA);
        ESLOAD(esA, kk + 4);
        __builtin_amdgcn_sched_barrier(0);
        MFMA_PHASE(avB, wbuf[1]);
        __builtin_amdgcn_sched_barrier(0);
        STAGE_WRITE(wbuf[0]);
        PIPE_BARRIER();
    }
    // tap 26: weights staged into wbuf0 by last O; avA gathered by last O
    MFMA_PHASE(avA, wbuf[0]);

#undef ESLOAD
#undef GATHER
#undef STAGE_LOAD
#undef STAGE_WRITE
#undef MFMA_PHASE
#undef PIPE_BARRIER

    // ---- store: D layout col = lane&15, row = q*4 + reg
    #pragma unroll
    for (int s = 0; s < 4; ++s) {
        int rowb = m0 + s*16 + q*4;
        #pragma unroll
        for (int r = 0; r < 4; ++r) {
            if (rowb + r < nvox) {
                unsigned short* yo = yout + (size_t)(rowb + r)*64 + l15;
                #pragma unroll
                for (int nt = 0; nt < 4; ++nt)
                    yo[nt*16] = f2bf(acc[s][nt][r]);
            }
        }
    }

    // ---- fused per-channel stats (pad rows have acc == 0)
    #pragma unroll
    for (int nt = 0; nt < 4; ++nt) {
        float s_ = 0.f, q_ = 0.f;
        #pragma unroll
        for (int s = 0; s < 4; ++s)
            #pragma unroll
            for (int r = 0; r < 4; ++r) {
                float v = acc[s][nt][r];
                s_ += v; q_ += v*v;
            }
        atomicAdd(&sred[nt*16 + l15], s_);
        atomicAdd(&sred[64 + nt*16 + l15], q_);
    }
    __syncthreads();
    if (t < 128) atomicAdd(&sums[t], sred[t]);
}

// ---------------- BN scale/bias ----------------
__global__ void finalize_kernel(const float* __restrict__ sums, const float* __restrict__ gamma,
                                const float* __restrict__ beta, float* __restrict__ ab, float invn) {
    int c = threadIdx.x;
    if (c < 64) {
        float mean = sums[c] * invn;
        float var  = sums[64 + c] * invn - mean*mean;
        float a = gamma[c] * rsqrtf(var + 1e-5f);
        ab[c] = a;
        ab[64 + c] = beta[c] - mean * a;
    }
}

// ---------------- BN1 + ReLU in place on y1 (bf16) ----------------
__global__ __launch_bounds__(256)
void bnrelu_kernel(unsigned short* __restrict__ y, const float* __restrict__ ab, int n4) {
    int i = blockIdx.x * blockDim.x + threadIdx.x;
    int stride = gridDim.x * blockDim.x;
    for (; i < n4; i += stride) {
        uint2 v = ((const uint2*)y)[i];
        int c0 = (i*4) & 63;
        float f0 = fmaxf(ab[c0]   * bf2f((unsigned short)(v.x & 0xffffu)) + ab[64 + c0],   0.f);
        float f1 = fmaxf(ab[c0+1] * bf2f((unsigned short)(v.x >> 16))     + ab[64 + c0+1], 0.f);
        float f2 = fmaxf(ab[c0+2] * bf2f((unsigned short)(v.y & 0xffffu)) + ab[64 + c0+2], 0.f);
        float f3 = fmaxf(ab[c0+3] * bf2f((unsigned short)(v.y >> 16))     + ab[64 + c0+3], 0.f);
        uint2 o;
        o.x = (unsigned int)f2bf(f0) | ((unsigned int)f2bf(f1) << 16);
        o.y = (unsigned int)f2bf(f2) | ((unsigned int)f2bf(f3) << 16);
        ((uint2*)y)[i] = o;
    }
}

// ---------------- epilogue: BN2 + identity + relu -> fp32 ----------------
__global__ __launch_bounds__(256)
void final_kernel(const unsigned short* __restrict__ y2, const float* __restrict__ feat,
                  const float* __restrict__ ab, float* __restrict__ out, int ntot2) {
    int i = blockIdx.x * blockDim.x + threadIdx.x;
    int stride = gridDim.x * blockDim.x;
    for (; i < ntot2; i += stride) {
        unsigned int v = ((const unsigned int*)y2)[i];
        int c0 = (i*2) & 63;
        float2 f = ((const float2*)feat)[i];
        float r0 = fmaxf(ab[c0]   * bf2f((unsigned short)(v & 0xffffu)) + ab[64 + c0]   + f.x, 0.f);
        float r1 = fmaxf(ab[c0+1] * bf2f((unsigned short)(v >> 16))     + ab[64 + c0+1] + f.y, 0.f);
        ((float2*)out)[i] = make_float2(r0, r1);
    }
}

extern "C" void kernel_launch(void* const* d_in, const int* in_sizes, int n_in,
                              void* d_out, int out_size, void* d_ws, size_t ws_size,
                              hipStream_t stream) {
    const float* features = (const float*)d_in[0];
    const int*   nbr      = (const int*)d_in[1];
    const float* valid    = (const float*)d_in[2];
    const float* W1       = (const float*)d_in[3];
    const float* gamma1   = (const float*)d_in[4];
    const float* beta1    = (const float*)d_in[5];
    const float* W2       = (const float*)d_in[6];
    const float* gamma2   = (const float*)d_in[7];
    const float* beta2    = (const float*)d_in[8];
    float* out = (float*)d_out;

    int nvox  = in_sizes[0] / 64;                 // 500000
    int nvoxp = (nvox + 255) & ~255;              // 500224 (pad to block multiple)
    size_t featB = (size_t)nvox * 64 * 2;         // 64 MB bf16 feature map

    // d_out doubles as scratch until final_kernel overwrites all of it:
    //   [0, featB)        xb (bf16 features)
    //   [featB, 2*featB)  y1 (conv1 out, bf16; BN1+ReLU applied in place)
    char* ob = (char*)d_out;
    unsigned short* xb = (unsigned short*)ob;
    unsigned short* y1 = (unsigned short*)(ob + featB);

    // d_ws (~118.6 MB):
    //   [0, 2048)      stats: sums1, sums2, ab1, ab2 (128 floats each)
    //   [2048, 2176)   zero page (128 B)
    //   [4096, ..)     Wp1, Wp2 (216 KB each)
    //   [512K, +54MB)  enc (27 * nvoxp ints)
    //   then           y2 (bf16)
    char* ws = (char*)d_ws;
    float* stats = (float*)ws;
    float* sums1 = stats;
    float* sums2 = stats + 128;
    float* ab1   = stats + 256;
    float* ab2   = stats + 384;
    const unsigned short* zrow = (const unsigned short*)(ws + 2048);
    unsigned short* Wp1 = (unsigned short*)(ws + 4096);
    unsigned short* Wp2 = (unsigned short*)(ws + 4096 + 221184);
    int* enc = (int*)(ws + 524288);
    size_t encB = (size_t)27 * nvoxp * 4;          // 54,024,192
    unsigned short* y2 = (unsigned short*)(ws + 524288 + encB);

    hipMemsetAsync(ws, 0, 4096, stream);           // stats + zero page

    convert_bf16<<<2048, 256, 0, stream>>>(features, xb, nvox * 16);
    pack_w<<<54, 256, 0, stream>>>(W1, W2, Wp1, Wp2);
    dim3 eg(nvoxp / 256, 27);
    encode_kernel<<<eg, 256, 0, stream>>>(nbr, valid, enc, nvox, nvoxp);

    int convGrid = nvoxp / 256;   // 1954 blocks, 64 voxels/wave
    conv_kernel<<<convGrid, 256, 0, stream>>>(xb, enc, Wp1, zrow, y1, sums1, nvox, nvoxp);
    finalize_kernel<<<1, 64, 0, stream>>>(sums1, gamma1, beta1, ab1, 1.0f / nvox);
    bnrelu_kernel<<<2048, 256, 0, stream>>>(y1, ab1, nvox * 16);
    conv_kernel<<<convGrid, 256, 0, stream>>>(y1, enc, Wp2, zrow, y2, sums2, nvox, nvoxp);
    finalize_kernel<<<1, 64, 0, stream>>>(sums2, gamma2, beta2, ab2, 1.0f / nvox);
    final_kernel<<<4096, 256, 0, stream>>>(y2, features, ab2, out, nvox * 32);
}

// Round 5
// 771.204 us; speedup vs baseline: 1.6483x; 1.0381x over previous
//
#include <hip/hip_runtime.h>
#include <hip/hip_bf16.h>
#include <stdint.h>

typedef __attribute__((ext_vector_type(8))) short short8;
typedef __attribute__((ext_vector_type(4))) float floatx4;

__device__ __forceinline__ float bf2f(unsigned short u) {
    union { unsigned int ui; float f; } v; v.ui = ((unsigned int)u) << 16; return v.f;
}
__device__ __forceinline__ unsigned short f2bf(float f) {
    union { float f; unsigned int u; } v; v.f = f;
    unsigned int u = v.u;
    unsigned int r = (u + 0x7fffu + ((u >> 16) & 1u)) >> 16;
    return (unsigned short)r;
}

// ---------------- fused prologue: convert | pack_w | encode (independent jobs) ----
// blocks [0,2048):       features fp32 -> bf16 (grid-stride)
// blocks [2048,2102):    pack W1/W2 into B-fragment order
// blocks [2102,...):     encode enc[k][i] = valid ? idx : -1 (padded to nvoxp)
__global__ __launch_bounds__(256)
void prologue_kernel(const float* __restrict__ features, unsigned short* __restrict__ xb,
                     const int* __restrict__ nbr, const float* __restrict__ valid,
                     int* __restrict__ enc,
                     const float* __restrict__ W1, const float* __restrict__ W2,
                     unsigned short* __restrict__ Wp1, unsigned short* __restrict__ Wp2,
                     int nvox, int nvoxp, int n4) {
    int b = blockIdx.x;
    int t = threadIdx.x;
    if (b < 2048) {
        int i = b * 256 + t;
        for (; i < n4; i += 2048 * 256) {
            float4 v = ((const float4*)features)[i];
            ushort4 o;
            o.x = f2bf(v.x); o.y = f2bf(v.y); o.z = f2bf(v.z); o.w = f2bf(v.w);
            ((ushort4*)xb)[i] = o;
        }
    } else if (b < 2102) {
        int bi = b - 2048;               // 0..53
        const float* W = (bi < 27) ? W1 : W2;
        unsigned short* Wp = (bi < 27) ? Wp1 : Wp2;
        int kk = bi % 27;
        int lane = t & 63, grp = t >> 6;
        int q = lane >> 4, l15 = lane & 15;
        for (int c8 = grp; c8 < 8; c8 += 4) {
            int ks = c8 >> 2, nt = c8 & 3;
            // Wp[kk][ks][nt][lane][j] = W[kk][cin = ks*32+(lane>>4)*8+j][cout = nt*16+(lane&15)]
            unsigned short* dst = Wp + (((kk*2 + ks)*4 + nt)*64 + lane)*8;
            const float* src = W + kk*4096 + (ks*32 + q*8)*64 + nt*16 + l15;
            #pragma unroll
            for (int j = 0; j < 8; ++j) dst[j] = f2bf(src[j*64]);
        }
    } else {
        int e = b - 2102;
        int nblk = nvoxp >> 8;
        int k = e / nblk;
        int r = (e - k * nblk) * 256 + t;
        int v = -1;
        if (r < nvox) {
            float f = valid[(size_t)k * nvox + r];
            int ix = nbr[(size_t)k * nvox + r];
            v = (f != 0.f) ? ix : -1;
        }
        enc[(size_t)k * nvoxp + r] = v;
    }
}

// ---------------- gathered MFMA conv (round-0 structure: best measured) ----------
// block = 256 = 4 waves; wave: 64 voxels (4 subtiles of 16) x 64 out-ch.
__global__ __launch_bounds__(256, 4)
void conv_kernel(const unsigned short* __restrict__ xin, const int* __restrict__ enc,
                 const unsigned short* __restrict__ Wp, const unsigned short* __restrict__ zrow,
                 unsigned short* __restrict__ yout, float* __restrict__ sums,
                 int nvox, int nvoxp) {
    int t = threadIdx.x;
    int wave = t >> 6, lane = t & 63;
    int q = lane >> 4, l15 = lane & 15;
    int m0 = blockIdx.x * 256 + wave * 64;   // < nvoxp always (grid covers pad)

    floatx4 acc[4][4];
    #pragma unroll
    for (int s = 0; s < 4; ++s)
        #pragma unroll
        for (int nt = 0; nt < 4; ++nt) acc[s][nt] = (floatx4){0.f, 0.f, 0.f, 0.f};

    for (int kk = 0; kk < 27; ++kk) {
        // one coalesced load: lane holds enc for voxel m0+lane; distribute via bpermute
        int e_all = enc[(size_t)kk * nvoxp + m0 + lane];
        const unsigned short* rp[4];
        #pragma unroll
        for (int s = 0; s < 4; ++s) {
            int es = __builtin_amdgcn_ds_bpermute((s*16 + l15) * 4, e_all);
            rp[s] = (es >= 0) ? (xin + (size_t)es * 64) : zrow;   // zero page: A-row = 0
        }
        // issue all 8 gathers up front (branchless -> pipelineable)
        short8 av[2][4];
        #pragma unroll
        for (int ks = 0; ks < 2; ++ks)
            #pragma unroll
            for (int s = 0; s < 4; ++s)
                av[ks][s] = *(const short8*)(rp[s] + ks*32 + q*8);

        #pragma unroll
        for (int ks = 0; ks < 2; ++ks) {
            const unsigned short* wb = Wp + ((kk*2 + ks)*4)*512 + lane*8;
            #pragma unroll
            for (int nt = 0; nt < 4; ++nt) {
                short8 bv = *(const short8*)(wb + nt*512);
                #pragma unroll
                for (int s = 0; s < 4; ++s)
                    acc[s][nt] = __builtin_amdgcn_mfma_f32_16x16x32_bf16(av[ks][s], bv, acc[s][nt], 0, 0, 0);
            }
        }
    }

    // store: D layout col = lane&15, row = q*4 + reg
    #pragma unroll
    for (int s = 0; s < 4; ++s) {
        int rowb = m0 + s*16 + q*4;
        #pragma unroll
        for (int r = 0; r < 4; ++r) {
            if (rowb + r < nvox) {
                unsigned short* yo = yout + (size_t)(rowb + r)*64 + l15;
                #pragma unroll
                for (int nt = 0; nt < 4; ++nt)
                    yo[nt*16] = f2bf(acc[s][nt][r]);
            }
        }
    }

    // fused per-channel stats (pad rows have acc == 0: every tap hit the zero page)
    __shared__ float sred[128];
    if (t < 128) sred[t] = 0.f;
    __syncthreads();
    #pragma unroll
    for (int nt = 0; nt < 4; ++nt) {
        float s_ = 0.f, q_ = 0.f;
        #pragma unroll
        for (int s = 0; s < 4; ++s)
            #pragma unroll
            for (int r = 0; r < 4; ++r) {
                float v = acc[s][nt][r];
                s_ += v; q_ += v*v;
            }
        atomicAdd(&sred[nt*16 + l15], s_);
        atomicAdd(&sred[64 + nt*16 + l15], q_);
    }
    __syncthreads();
    if (t < 128) atomicAdd(&sums[t], sred[t]);
}

// ---------------- BN1 + ReLU in place on y1 (bf16), scale/bias computed inline ----
// Channel group of each thread is loop-invariant: stride*4 % 64 == 0.
__global__ __launch_bounds__(256)
void bnrelu_kernel(unsigned short* __restrict__ y, const float* __restrict__ sums,
                   const float* __restrict__ gamma, const float* __restrict__ beta,
                   float invn, int n4) {
    int i0 = blockIdx.x * blockDim.x + threadIdx.x;
    int c0 = (i0 * 4) & 63;
    float a[4], bb[4];
    #pragma unroll
    for (int j = 0; j < 4; ++j) {
        int c = c0 + j;
        float mean = sums[c] * invn;
        float var  = sums[64 + c] * invn - mean * mean;
        float aa = gamma[c] * rsqrtf(var + 1e-5f);
        a[j] = aa; bb[j] = beta[c] - mean * aa;
    }
    int stride = gridDim.x * blockDim.x;
    for (int i = i0; i < n4; i += stride) {
        uint2 v = ((const uint2*)y)[i];
        float f0 = fmaxf(a[0] * bf2f((unsigned short)(v.x & 0xffffu)) + bb[0], 0.f);
        float f1 = fmaxf(a[1] * bf2f((unsigned short)(v.x >> 16))     + bb[1], 0.f);
        float f2 = fmaxf(a[2] * bf2f((unsigned short)(v.y & 0xffffu)) + bb[2], 0.f);
        float f3 = fmaxf(a[3] * bf2f((unsigned short)(v.y >> 16))     + bb[3], 0.f);
        uint2 o;
        o.x = (unsigned int)f2bf(f0) | ((unsigned int)f2bf(f1) << 16);
        o.y = (unsigned int)f2bf(f2) | ((unsigned int)f2bf(f3) << 16);
        ((uint2*)y)[i] = o;
    }
}

// ---------------- epilogue: BN2 + identity + relu -> fp32, scale/bias inline ------
__global__ __launch_bounds__(256)
void final_kernel(const unsigned short* __restrict__ y2, const float* __restrict__ feat,
                  const float* __restrict__ sums, const float* __restrict__ gamma,
                  const float* __restrict__ beta, float invn,
                  float* __restrict__ out, int ntot2) {
    int i0 = blockIdx.x * blockDim.x + threadIdx.x;
    int c0 = (i0 * 2) & 63;
    float a[2], bb[2];
    #pragma unroll
    for (int j = 0; j < 2; ++j) {
        int c = c0 + j;
        float mean = sums[c] * invn;
        float var  = sums[64 + c] * invn - mean * mean;
        float aa = gamma[c] * rsqrtf(var + 1e-5f);
        a[j] = aa; bb[j] = beta[c] - mean * aa;
    }
    int stride = gridDim.x * blockDim.x;
    for (int i = i0; i < ntot2; i += stride) {
        unsigned int v = ((const unsigned int*)y2)[i];
        float2 f = ((const float2*)feat)[i];
        float r0 = fmaxf(a[0] * bf2f((unsigned short)(v & 0xffffu)) + bb[0] + f.x, 0.f);
        float r1 = fmaxf(a[1] * bf2f((unsigned short)(v >> 16))     + bb[1] + f.y, 0.f);
        ((float2*)out)[i] = make_float2(r0, r1);
    }
}

extern "C" void kernel_launch(void* const* d_in, const int* in_sizes, int n_in,
                              void* d_out, int out_size, void* d_ws, size_t ws_size,
                              hipStream_t stream) {
    const float* features = (const float*)d_in[0];
    const int*   nbr      = (const int*)d_in[1];
    const float* valid    = (const float*)d_in[2];
    const float* W1       = (const float*)d_in[3];
    const float* gamma1   = (const float*)d_in[4];
    const float* beta1    = (const float*)d_in[5];
    const float* W2       = (const float*)d_in[6];
    const float* gamma2   = (const float*)d_in[7];
    const float* beta2    = (const float*)d_in[8];
    float* out = (float*)d_out;

    int nvox  = in_sizes[0] / 64;                 // 500000
    int nvoxp = (nvox + 255) & ~255;              // 500224 (pad to block multiple)
    size_t featB = (size_t)nvox * 64 * 2;         // 64 MB bf16 feature map

    // d_out doubles as scratch until final_kernel overwrites all of it:
    //   [0, featB)        xb (bf16 features)
    //   [featB, 2*featB)  y1 (conv1 out, bf16; BN1+ReLU applied in place)
    char* ob = (char*)d_out;
    unsigned short* xb = (unsigned short*)ob;
    unsigned short* y1 = (unsigned short*)(ob + featB);

    // d_ws (~118.6 MB):
    //   [0, 2048)      stats: sums1, sums2 (128 floats each) + spare
    //   [2048, 2176)   zero page (128 B)
    //   [4096, ..)     Wp1, Wp2 (216 KB each)
    //   [512K, +54MB)  enc (27 * nvoxp ints)
    //   then           y2 (bf16)
    char* ws = (char*)d_ws;
    float* stats = (float*)ws;
    float* sums1 = stats;
    float* sums2 = stats + 128;
    const unsigned short* zrow = (const unsigned short*)(ws + 2048);
    unsigned short* Wp1 = (unsigned short*)(ws + 4096);
    unsigned short* Wp2 = (unsigned short*)(ws + 4096 + 221184);
    int* enc = (int*)(ws + 524288);
    size_t encB = (size_t)27 * nvoxp * 4;          // 54,024,192
    unsigned short* y2 = (unsigned short*)(ws + 524288 + encB);

    hipMemsetAsync(ws, 0, 4096, stream);           // stats + zero page

    int nblk = nvoxp / 256;                        // 1954
    int prologueGrid = 2102 + 27 * nblk;           // convert | pack | encode
    prologue_kernel<<<prologueGrid, 256, 0, stream>>>(
        features, xb, nbr, valid, enc, W1, W2, Wp1, Wp2, nvox, nvoxp, nvox * 16);

    conv_kernel<<<nblk, 256, 0, stream>>>(xb, enc, Wp1, zrow, y1, sums1, nvox, nvoxp);
    bnrelu_kernel<<<2048, 256, 0, stream>>>(y1, sums1, gamma1, beta1, 1.0f / nvox, nvox * 16);
    conv_kernel<<<nblk, 256, 0, stream>>>(y1, enc, Wp2, zrow, y2, sums2, nvox, nvoxp);
    final_kernel<<<4096, 256, 0, stream>>>(y2, features, sums2, gamma2, beta2, 1.0f / nvox,
                                           out, nvox * 32);
}